// Round 6
// baseline (229.726 us; speedup 1.0000x reference)
//
#include <hip/hip_runtime.h>
#include <math.h>

#define D 128
#define K 10
#define NB1 2048
#define TPB 256
#define LPR 16                      // lanes per row
#define ROWS_PER_TILE 32            // 2 rows per thread per iteration

typedef float f4 __attribute__((ext_vector_type(4)));

__device__ __forceinline__ f4 ld16(const float* p) {
    return *(const f4*)p;           // plain cached load (no nt)
}

// Sorted ascending top-K insert, fully unrolled (static indices -> stays in VGPRs).
__device__ __forceinline__ void topk_insert(float (&t)[K], float d) {
    if (d < t[K - 1]) {
        t[K - 1] = d;
#pragma unroll
        for (int j = K - 1; j > 0; --j) {
            float a = t[j - 1], b = t[j];
            t[j - 1] = fminf(a, b);
            t[j]     = fmaxf(a, b);
        }
    }
}

__device__ __forceinline__ float rowdist(f4 a0, f4 a1, f4 xa, f4 xb) {
    f4 d0 = a0 - xa;
    f4 d1 = a1 - xb;
    float d = d0.x * d0.x + d0.y * d0.y + d0.z * d0.z + d0.w * d0.w;
    d += d1.x * d1.x + d1.y * d1.y + d1.z * d1.z + d1.w * d1.w;
#pragma unroll
    for (int m = 1; m < LPR; m <<= 1) d += __shfl_xor(d, m);
    return d;
}

__global__ __launch_bounds__(TPB) void knn_stage1(
    const float* __restrict__ x,
    const float* __restrict__ data,
    int nrows,
    float* __restrict__ ws) {
    const int t   = threadIdx.x;
    const int grp = t / LPR;          // 0..15
    const int ln  = t % LPR;          // 0..15
    const int c0  = ln * 4;
    const f4 xa = *(const f4*)(x + c0);
    const f4 xb = *(const f4*)(x + c0 + 64);

    float best[K];
#pragma unroll
    for (int i = 0; i < K; ++i) best[i] = INFINITY;

    const int G          = gridDim.x;
    const int full_tiles = nrows / ROWS_PER_TILE;
    const size_t rhalf   = (size_t)16 * D;          // second row of the pair
    const size_t tstep   = (size_t)ROWS_PER_TILE * D;  // 16 KB contiguous step

    // contiguous per-block partition: block b owns tiles [b*per, b*per+per)
    const int per = (full_tiles + G - 1) / G;
    const int t0  = blockIdx.x * per;
    const int t1  = (t0 + per < full_tiles) ? (t0 + per) : full_tiles;

    if (t0 < t1) {
        const float* p = data + (size_t)(t0 * ROWS_PER_TILE + grp) * D + c0;
        f4 a0 = ld16(p);
        f4 a1 = ld16(p + 64);
        f4 a2 = ld16(p + rhalf);
        f4 a3 = ld16(p + rhalf + 64);
        for (int tile = t0 + 1; tile < t1; ++tile) {
            p += tstep;
            f4 b0 = ld16(p);              // prefetch next tile (8 loads in flight)
            f4 b1 = ld16(p + 64);
            f4 b2 = ld16(p + rhalf);
            f4 b3 = ld16(p + rhalf + 64);
            float d0 = rowdist(a0, a1, xa, xb);
            float d1 = rowdist(a2, a3, xa, xb);
            if (ln == 0) { topk_insert(best, d0); topk_insert(best, d1); }
            a0 = b0; a1 = b1; a2 = b2; a3 = b3;
        }
        float d0 = rowdist(a0, a1, xa, xb);
        float d1 = rowdist(a2, a3, xa, xb);
        if (ln == 0) { topk_insert(best, d0); topk_insert(best, d1); }
    }

    // tail rows (nrows % 32) — block 0 only; each grp covers base+grp, base+grp+16
    if (blockIdx.x == 0) {
        for (int row = full_tiles * ROWS_PER_TILE + grp; row < nrows; row += 16) {
            const float* p = data + (size_t)row * D + c0;
            f4 a0 = ld16(p);
            f4 a1 = ld16(p + 64);
            float d = rowdist(a0, a1, xa, xb);
            if (ln == 0) topk_insert(best, d);
        }
    }

    // merge the 16 per-group lists inside the block
    __shared__ float lmerge[16 * K];
    if (ln == 0) {
#pragma unroll
        for (int i = 0; i < K; ++i) lmerge[grp * K + i] = best[i];
    }
    __syncthreads();
    if (t == 0) {
        float fin[K];
#pragma unroll
        for (int i = 0; i < K; ++i) fin[i] = INFINITY;
        for (int i = 0; i < 16 * K; ++i) topk_insert(fin, lmerge[i]);
#pragma unroll
        for (int i = 0; i < K; ++i) ws[(size_t)blockIdx.x * K + i] = fin[i];
    }
}

__global__ __launch_bounds__(TPB) void knn_stage2(
    const float* __restrict__ x,
    const float* __restrict__ y,
    const float* __restrict__ ws,
    int m,
    float* __restrict__ out) {
    const int t    = threadIdx.x;
    const int lane = t & 63;
    const int wid  = t >> 6;

    __shared__ float vals[TPB * K];
    __shared__ float red[TPB];
    __shared__ float rmin[TPB / 64];
    __shared__ int   rmini[TPB / 64];

    float best[K];
#pragma unroll
    for (int i = 0; i < K; ++i) best[i] = INFINITY;
    for (int i = t; i < m; i += TPB) topk_insert(best, ws[i]);
#pragma unroll
    for (int i = 0; i < K; ++i) vals[t * K + i] = best[i];

    // ||x - y||^2 reduce
    float dxy = 0.f;
    if (t < D) { float d = x[t] - y[t]; dxy = d * d; }
    red[t] = dxy;
    __syncthreads();
    for (int s = TPB / 2; s > 0; s >>= 1) {
        if (t < s) red[t] += red[t + s];
        __syncthreads();
    }
    float norm_xy = sqrtf(red[0]);

    // 10 rounds of parallel argmin-extract over vals[]
    float sum10 = 0.f;
#pragma unroll 1
    for (int it = 0; it < K; ++it) {
        __syncthreads();
        float mn = INFINITY;
        int   mi = -1;
#pragma unroll
        for (int j = 0; j < K; ++j) {
            float v = vals[t * K + j];
            if (v < mn) { mn = v; mi = t * K + j; }
        }
#pragma unroll
        for (int msk = 1; msk < 64; msk <<= 1) {
            float om = __shfl_xor(mn, msk);
            int   oi = __shfl_xor(mi, msk);
            if (om < mn) { mn = om; mi = oi; }
        }
        if (lane == 0) { rmin[wid] = mn; rmini[wid] = mi; }
        __syncthreads();
        if (t == 0) {
            float gmn = rmin[0];
            int   gmi = rmini[0];
#pragma unroll
            for (int w = 1; w < TPB / 64; ++w) {
                if (rmin[w] < gmn) { gmn = rmin[w]; gmi = rmini[w]; }
            }
            sum10 += sqrtf(gmn);
            vals[gmi] = INFINITY;
        }
    }
    if (t == 0) out[0] = norm_xy * 0.5f + sum10 / (float)K;
}

// Safety fallback: everything in one block (used only if ws is too small).
__global__ __launch_bounds__(TPB) void knn_all(
    const float* __restrict__ x,
    const float* __restrict__ y,
    const float* __restrict__ data,
    int nrows,
    float* __restrict__ out) {
    const int t   = threadIdx.x;
    const int grp = t / LPR;
    const int ln  = t % LPR;
    const int c0  = ln * 4;
    const f4 xa = *(const f4*)(x + c0);
    const f4 xb = *(const f4*)(x + c0 + 64);

    float best[K];
#pragma unroll
    for (int i = 0; i < K; ++i) best[i] = INFINITY;

    for (int row = grp; row < nrows; row += 16) {
        const float* p = data + (size_t)row * D + c0;
        f4 a0 = ld16(p);
        f4 a1 = ld16(p + 64);
        float d = rowdist(a0, a1, xa, xb);
        if (ln == 0) topk_insert(best, d);
    }

    __shared__ float lmerge[16 * K];
    __shared__ float red[TPB];
    if (ln == 0) {
#pragma unroll
        for (int i = 0; i < K; ++i) lmerge[grp * K + i] = best[i];
    }
    float dxy = 0.f;
    if (t < D) { float d = x[t] - y[t]; dxy = d * d; }
    red[t] = dxy;
    __syncthreads();
    for (int s = TPB / 2; s > 0; s >>= 1) {
        if (t < s) red[t] += red[t + s];
        __syncthreads();
    }
    if (t == 0) {
        float fin[K];
#pragma unroll
        for (int i = 0; i < K; ++i) fin[i] = INFINITY;
        for (int i = 0; i < 16 * K; ++i) topk_insert(fin, lmerge[i]);
        float sum10 = 0.f;
#pragma unroll
        for (int i = 0; i < K; ++i) sum10 += sqrtf(fin[i]);
        out[0] = sqrtf(red[0]) * 0.5f + sum10 / (float)K;
    }
}

extern "C" void kernel_launch(void* const* d_in, const int* in_sizes, int n_in,
                              void* d_out, int out_size, void* d_ws, size_t ws_size,
                              hipStream_t stream) {
    const float* x    = (const float*)d_in[0];
    const float* y    = (const float*)d_in[1];
    const float* data = (const float*)d_in[2];
    float* out        = (float*)d_out;
    const int nrows   = in_sizes[2] / D;

    const size_t per_block = (size_t)K * sizeof(float);
    if (ws_size >= per_block * 64) {
        int nblocks = (int)((ws_size / per_block < (size_t)NB1)
                                ? (ws_size / per_block)
                                : (size_t)NB1);
        float* ws = (float*)d_ws;
        knn_stage1<<<dim3(nblocks), dim3(TPB), 0, stream>>>(x, data, nrows, ws);
        knn_stage2<<<dim3(1), dim3(TPB), 0, stream>>>(x, y, ws, nblocks * K, out);
    } else {
        knn_all<<<dim3(1), dim3(TPB), 0, stream>>>(x, y, data, nrows, out);
    }
}

// Round 7
// 203.098 us; speedup vs baseline: 1.1311x; 1.1311x over previous
//
#include <hip/hip_runtime.h>
#include <math.h>

#define D 128
#define K 10
#define NB1 2048
#define TPB 256
#define LPR 16                      // lanes per row
#define ROWS_PER_TILE 32            // 2 rows per thread per iteration

typedef float f4 __attribute__((ext_vector_type(4)));

__device__ __forceinline__ f4 ldnt(const float* p) {
    return __builtin_nontemporal_load((const f4*)p);
}

// Sorted ascending top-K insert, fully unrolled (static indices -> stays in VGPRs).
__device__ __forceinline__ void topk_insert(float (&t)[K], float d) {
    if (d < t[K - 1]) {
        t[K - 1] = d;
#pragma unroll
        for (int j = K - 1; j > 0; --j) {
            float a = t[j - 1], b = t[j];
            t[j - 1] = fminf(a, b);
            t[j]     = fmaxf(a, b);
        }
    }
}

__device__ __forceinline__ float rowdist(f4 a0, f4 a1, f4 xa, f4 xb) {
    f4 d0 = a0 - xa;
    f4 d1 = a1 - xb;
    float d = d0.x * d0.x + d0.y * d0.y + d0.z * d0.z + d0.w * d0.w;
    d += d1.x * d1.x + d1.y * d1.y + d1.z * d1.z + d1.w * d1.w;
#pragma unroll
    for (int m = 1; m < LPR; m <<= 1) d += __shfl_xor(d, m);
    return d;
}

__global__ __launch_bounds__(TPB) void knn_stage1(
    const float* __restrict__ x,
    const float* __restrict__ data,
    int nrows,
    float* __restrict__ ws) {
    const int t   = threadIdx.x;
    const int grp = t / LPR;          // 0..15
    const int ln  = t % LPR;          // 0..15
    const int c0  = ln * 4;
    const f4 xa = *(const f4*)(x + c0);
    const f4 xb = *(const f4*)(x + c0 + 64);

    float best[K];
#pragma unroll
    for (int i = 0; i < K; ++i) best[i] = INFINITY;

    const int G          = gridDim.x;
    const int full_tiles = nrows / ROWS_PER_TILE;
    const size_t rhalf   = (size_t)16 * D;   // second row of the pair

    int tile = blockIdx.x;
    if (tile < full_tiles) {
        const float* p = data + (size_t)(tile * ROWS_PER_TILE + grp) * D + c0;
        f4 a0 = ldnt(p);
        f4 a1 = ldnt(p + 64);
        f4 a2 = ldnt(p + rhalf);
        f4 a3 = ldnt(p + rhalf + 64);
        int next = tile + G;
        const size_t step = (size_t)G * ROWS_PER_TILE * D;
        while (next < full_tiles) {
            p += step;
            f4 b0 = ldnt(p);              // prefetch next tile (8 loads in flight)
            f4 b1 = ldnt(p + 64);
            f4 b2 = ldnt(p + rhalf);
            f4 b3 = ldnt(p + rhalf + 64);
            float d0 = rowdist(a0, a1, xa, xb);
            float d1 = rowdist(a2, a3, xa, xb);
            if (ln == 0) { topk_insert(best, d0); topk_insert(best, d1); }
            a0 = b0; a1 = b1; a2 = b2; a3 = b3;
            next += G;
        }
        float d0 = rowdist(a0, a1, xa, xb);
        float d1 = rowdist(a2, a3, xa, xb);
        if (ln == 0) { topk_insert(best, d0); topk_insert(best, d1); }
    }

    // tail rows (nrows % 32) — block 0 only; each grp covers base+grp, base+grp+16
    if (blockIdx.x == 0) {
        for (int row = full_tiles * ROWS_PER_TILE + grp; row < nrows; row += 16) {
            const float* p = data + (size_t)row * D + c0;
            f4 a0 = ldnt(p);
            f4 a1 = ldnt(p + 64);
            float d = rowdist(a0, a1, xa, xb);
            if (ln == 0) topk_insert(best, d);
        }
    }

    // merge the 16 per-group lists inside the block
    __shared__ float lmerge[16 * K];
    if (ln == 0) {
#pragma unroll
        for (int i = 0; i < K; ++i) lmerge[grp * K + i] = best[i];
    }
    __syncthreads();
    if (t == 0) {
        float fin[K];
#pragma unroll
        for (int i = 0; i < K; ++i) fin[i] = INFINITY;
        for (int i = 0; i < 16 * K; ++i) topk_insert(fin, lmerge[i]);
#pragma unroll
        for (int i = 0; i < K; ++i) ws[(size_t)blockIdx.x * K + i] = fin[i];
    }
}

__global__ __launch_bounds__(TPB) void knn_stage2(
    const float* __restrict__ x,
    const float* __restrict__ y,
    const float* __restrict__ ws,
    int m,
    float* __restrict__ out) {
    const int t    = threadIdx.x;
    const int lane = t & 63;
    const int wid  = t >> 6;

    __shared__ float vals[TPB * K];
    __shared__ float red[TPB];
    __shared__ float rmin[TPB / 64];
    __shared__ int   rmini[TPB / 64];

    float best[K];
#pragma unroll
    for (int i = 0; i < K; ++i) best[i] = INFINITY;
    for (int i = t; i < m; i += TPB) topk_insert(best, ws[i]);
#pragma unroll
    for (int i = 0; i < K; ++i) vals[t * K + i] = best[i];

    // ||x - y||^2 reduce
    float dxy = 0.f;
    if (t < D) { float d = x[t] - y[t]; dxy = d * d; }
    red[t] = dxy;
    __syncthreads();
    for (int s = TPB / 2; s > 0; s >>= 1) {
        if (t < s) red[t] += red[t + s];
        __syncthreads();
    }
    float norm_xy = sqrtf(red[0]);

    // 10 rounds of parallel argmin-extract over vals[]
    float sum10 = 0.f;
#pragma unroll 1
    for (int it = 0; it < K; ++it) {
        __syncthreads();
        float mn = INFINITY;
        int   mi = -1;
#pragma unroll
        for (int j = 0; j < K; ++j) {
            float v = vals[t * K + j];
            if (v < mn) { mn = v; mi = t * K + j; }
        }
#pragma unroll
        for (int msk = 1; msk < 64; msk <<= 1) {
            float om = __shfl_xor(mn, msk);
            int   oi = __shfl_xor(mi, msk);
            if (om < mn) { mn = om; mi = oi; }
        }
        if (lane == 0) { rmin[wid] = mn; rmini[wid] = mi; }
        __syncthreads();
        if (t == 0) {
            float gmn = rmin[0];
            int   gmi = rmini[0];
#pragma unroll
            for (int w = 1; w < TPB / 64; ++w) {
                if (rmin[w] < gmn) { gmn = rmin[w]; gmi = rmini[w]; }
            }
            sum10 += sqrtf(gmn);
            vals[gmi] = INFINITY;
        }
    }
    if (t == 0) out[0] = norm_xy * 0.5f + sum10 / (float)K;
}

// Safety fallback: everything in one block (used only if ws is too small).
__global__ __launch_bounds__(TPB) void knn_all(
    const float* __restrict__ x,
    const float* __restrict__ y,
    const float* __restrict__ data,
    int nrows,
    float* __restrict__ out) {
    const int t   = threadIdx.x;
    const int grp = t / LPR;
    const int ln  = t % LPR;
    const int c0  = ln * 4;
    const f4 xa = *(const f4*)(x + c0);
    const f4 xb = *(const f4*)(x + c0 + 64);

    float best[K];
#pragma unroll
    for (int i = 0; i < K; ++i) best[i] = INFINITY;

    for (int row = grp; row < nrows; row += 16) {
        const float* p = data + (size_t)row * D + c0;
        f4 a0 = ldnt(p);
        f4 a1 = ldnt(p + 64);
        float d = rowdist(a0, a1, xa, xb);
        if (ln == 0) topk_insert(best, d);
    }

    __shared__ float lmerge[16 * K];
    __shared__ float red[TPB];
    if (ln == 0) {
#pragma unroll
        for (int i = 0; i < K; ++i) lmerge[grp * K + i] = best[i];
    }
    float dxy = 0.f;
    if (t < D) { float d = x[t] - y[t]; dxy = d * d; }
    red[t] = dxy;
    __syncthreads();
    for (int s = TPB / 2; s > 0; s >>= 1) {
        if (t < s) red[t] += red[t + s];
        __syncthreads();
    }
    if (t == 0) {
        float fin[K];
#pragma unroll
        for (int i = 0; i < K; ++i) fin[i] = INFINITY;
        for (int i = 0; i < 16 * K; ++i) topk_insert(fin, lmerge[i]);
        float sum10 = 0.f;
#pragma unroll
        for (int i = 0; i < K; ++i) sum10 += sqrtf(fin[i]);
        out[0] = sqrtf(red[0]) * 0.5f + sum10 / (float)K;
    }
}

extern "C" void kernel_launch(void* const* d_in, const int* in_sizes, int n_in,
                              void* d_out, int out_size, void* d_ws, size_t ws_size,
                              hipStream_t stream) {
    const float* x    = (const float*)d_in[0];
    const float* y    = (const float*)d_in[1];
    const float* data = (const float*)d_in[2];
    float* out        = (float*)d_out;
    const int nrows   = in_sizes[2] / D;

    const size_t per_block = (size_t)K * sizeof(float);
    if (ws_size >= per_block * 64) {
        int nblocks = (int)((ws_size / per_block < (size_t)NB1)
                                ? (ws_size / per_block)
                                : (size_t)NB1);
        float* ws = (float*)d_ws;
        knn_stage1<<<dim3(nblocks), dim3(TPB), 0, stream>>>(x, data, nrows, ws);
        knn_stage2<<<dim3(1), dim3(TPB), 0, stream>>>(x, y, ws, nblocks * K, out);
    } else {
        knn_all<<<dim3(1), dim3(TPB), 0, stream>>>(x, y, data, nrows, out);
    }
}